// Round 6
// baseline (113.755 us; speedup 1.0000x reference)
//
#include <hip/hip_runtime.h>
#include <math.h>

#define KK 8
#define LOG2E  1.4426950408889634f
#define HL2E   0.7213475204444817f   // 0.5 * log2(e)
#define LOG2PI 1.8378770664093453f

// ---------------------------------------------------------------------------
// MEASUREMENT ROUND: the density+softmax body runs 4x per chunk (rep 0 -> real
// acc; reps 1-3 -> dummy acc2 on bias-perturbed inputs, folded in only under a
// runtime-impossible branch). Real output path identical to the passing R5
// math (W-form solve, max-subtracted softmax). Purpose: make gmm_main ~4x its
// true duration so it enters the rocprof top-5 with full counters, and make
// dur_us = base + 3*main_1x resolvable.
// NOTE: per-point softmax MUST keep max-subtraction (R3 bug: collective exp2
// underflow zeroes responsibility mass).
// NOTE: no 2nd __launch_bounds__ arg (R4: treated as min-blocks/CU -> VGPR=64
// -> 458 MB/dispatch scratch spill).
// ---------------------------------------------------------------------------
__global__ __launch_bounds__(512) void gmm_main(const float* __restrict__ phi,
                                                const float* __restrict__ X,
                                                float* __restrict__ z,
                                                int B) {
    __shared__ float4 sp[KK][4];   // per-component params (broadcast reads)
    __shared__ float swr[8][KK];   // per-wave resp partials

    const int m = blockIdx.x;
    const int t = threadIdx.x;
    const float* row = phi + m * 120;

    if (t < KK) {
        // softmax over pi_tilde (redundant across 8 lanes, cheap)
        float mx = row[0];
        #pragma unroll
        for (int j = 1; j < KK; ++j) mx = fmaxf(mx, row[j]);
        float s = 0.f;
        #pragma unroll
        for (int j = 0; j < KK; ++j) s += __expf(row[j] - mx);
        float pik = __expf(row[t] - mx) / s;
        z[m * 80 + 64 + t] = pik;                       // pi columns

        const float* muk = row + 8 + t * 4;
        const float* Lv  = row + 40 + t * 10;
        // tril(D=4) order: l00,l10,l11,l20,l21,l22,l30,l31,l32,l33
        float l00 = Lv[0], l10 = Lv[1], l11 = Lv[2], l20 = Lv[3], l21 = Lv[4],
              l22 = Lv[5], l30 = Lv[6], l31 = Lv[7], l32 = Lv[8], l33 = Lv[9];
        float i0 = 1.f / l00, i1 = 1.f / l11, i2 = 1.f / l22, i3 = 1.f / l33;
        // W = inv(L), lower triangular (== forward-substitution coefficients)
        float w00 = i0;
        float w10 = -i1 * l10 * w00;
        float w11 = i1;
        float w20 = -i2 * (l20 * w00 + l21 * w10);
        float w21 = -i2 * (l21 * w11);
        float w22 = i2;
        float w30 = -i3 * (l30 * w00 + l31 * w10 + l32 * w20);
        float w31 = -i3 * (l31 * w11 + l32 * w21);
        float w32 = -i3 * (l32 * w22);
        float w33 = i3;
        float logdet = 2.f * (__logf(fmaxf(fabsf(l00), 1e-8f)) +
                              __logf(fmaxf(fabsf(l11), 1e-8f)) +
                              __logf(fmaxf(fabsf(l22), 1e-8f)) +
                              __logf(fmaxf(fabsf(l33), 1e-8f)));
        float c2 = (__logf(fmaxf(pik, 1e-8f)) -
                    0.5f * (4.f * LOG2PI + logdet)) * LOG2E;
        sp[t][0] = make_float4(muk[0], muk[1], muk[2], muk[3]);
        sp[t][1] = make_float4(w00, w10, w11, w20);
        sp[t][2] = make_float4(w21, w22, w30, w31);
        sp[t][3] = make_float4(w32, w33, c2, 0.f);
    } else if (t >= 64 && t < 96) {                     // mu columns
        int j = t - 64;
        z[m * 80 + j] = row[8 + j];
    } else if (t >= 96 && t < 128) {                    // log|L_diag| columns
        int j = t - 96, k = j >> 2, d = j & 3;
        int didx = (d == 0) ? 0 : (d == 1) ? 2 : (d == 2) ? 5 : 9;
        z[m * 80 + 32 + j] = __logf(fmaxf(fabsf(row[40 + k * 10 + didx]), 1e-6f));
    }
    __syncthreads();

    float acc[KK], acc2[KK];
    #pragma unroll
    for (int k = 0; k < KK; ++k) { acc[k] = 0.f; acc2[k] = 0.f; }

    const float4* X4 = reinterpret_cast<const float4*>(X);
    for (int base = 0; base < B; base += 2048) {
        float4 xv[4];
        #pragma unroll
        for (int i = 0; i < 4; ++i) xv[i] = X4[base + i * 512 + t];

        #pragma unroll
        for (int rep = 0; rep < 4; ++rep) {
            // reps 1-3: dummy work on perturbed inputs (defeats CSE with rep 0)
            float4 xw[4];
            #pragma unroll
            for (int i = 0; i < 4; ++i) {
                xw[i] = xv[i];
                if (rep) {
                    float bias = (float)rep * 1e-30f;
                    xw[i].x += bias; xw[i].y += bias;
                    xw[i].z += bias; xw[i].w += bias;
                }
            }

            float lj[4][KK];
            #pragma unroll
            for (int k = 0; k < KK; ++k) {
                float4 p0 = sp[k][0], p1 = sp[k][1], p2 = sp[k][2], p3 = sp[k][3];
                // mu=p0; w00,w10,w11,w20=p1; w21,w22,w30,w31=p2; w32,w33,c2=p3
                #pragma unroll
                for (int i = 0; i < 4; ++i) {
                    float d0 = xw[i].x - p0.x;
                    float d1 = xw[i].y - p0.y;
                    float d2 = xw[i].z - p0.z;
                    float d3 = xw[i].w - p0.w;
                    float a0 = d0 * p1.x;
                    float a1 = fmaf(p1.y, d0, d1 * p1.z);
                    float a2 = fmaf(p1.w, d0, fmaf(p2.x, d1, d2 * p2.y));
                    float a3 = fmaf(p2.z, d0, fmaf(p2.w, d1, fmaf(p3.x, d2, d3 * p3.y)));
                    float sq = fmaf(a0, a0, fmaf(a1, a1, fmaf(a2, a2, a3 * a3)));
                    lj[i][k] = fmaf(-HL2E, sq, p3.z);    // log2-domain
                }
            }
            #pragma unroll
            for (int i = 0; i < 4; ++i) {
                float mx = lj[i][0];
                #pragma unroll
                for (int k = 1; k < KK; ++k) mx = fmaxf(mx, lj[i][k]);
                float e[KK], s = 0.f;
                #pragma unroll
                for (int k = 0; k < KK; ++k) { e[k] = exp2f(lj[i][k] - mx); s += e[k]; }
                float inv = __builtin_amdgcn_rcpf(s);    // s >= 1 (max term = 1)
                if (rep == 0) {
                    #pragma unroll
                    for (int k = 0; k < KK; ++k) acc[k] = fmaf(e[k], inv, acc[k]);
                } else {
                    #pragma unroll
                    for (int k = 0; k < KK; ++k) acc2[k] = fmaf(e[k], inv, acc2[k]);
                }
            }
        }
    }

    // never true for this data (phi ~ N(0,1)); keeps acc2 chain alive
    if (phi[0] > 1e30f) {
        #pragma unroll
        for (int k = 0; k < KK; ++k) acc[k] += acc2[k];
    }

    // block reduction of resp accumulators
    #pragma unroll
    for (int k = 0; k < KK; ++k) {
        float v = acc[k];
        #pragma unroll
        for (int off = 32; off; off >>= 1) v += __shfl_xor(v, off, 64);
        acc[k] = v;
    }
    if ((t & 63) == 0) {
        int wid = t >> 6;
        #pragma unroll
        for (int k = 0; k < KK; ++k) swr[wid][k] = acc[k];
    }
    __syncthreads();
    if (t < KK) {
        float s = 0.f;
        #pragma unroll
        for (int w = 0; w < 8; ++w) s += swr[w][t];
        z[m * 80 + 72 + t] = s / (float)B;               // resp columns
    }
}

// ---------------------------------------------------------------------------
// Kernel 2: in-place column normalization of z (M=512 rows x 80 cols), ddof=1.
// ---------------------------------------------------------------------------
__global__ __launch_bounds__(512) void gmm_norm(float* __restrict__ z, int M) {
    __shared__ float sw[8];
    const int col = blockIdx.x;
    const int t = threadIdx.x;

    float v = z[t * 80 + col];

    float r = v;
    #pragma unroll
    for (int off = 32; off; off >>= 1) r += __shfl_xor(r, off, 64);
    if ((t & 63) == 0) sw[t >> 6] = r;
    __syncthreads();
    float tot = 0.f;
    #pragma unroll
    for (int w = 0; w < 8; ++w) tot += sw[w];
    float mean = tot / (float)M;
    __syncthreads();

    float d = v - mean;
    r = d * d;
    #pragma unroll
    for (int off = 32; off; off >>= 1) r += __shfl_xor(r, off, 64);
    if ((t & 63) == 0) sw[t >> 6] = r;
    __syncthreads();
    float tot2 = 0.f;
    #pragma unroll
    for (int w = 0; w < 8; ++w) tot2 += sw[w];
    float stdv = fmaxf(sqrtf(tot2 / (float)(M - 1)), 1e-6f);

    z[t * 80 + col] = d / stdv;
}

extern "C" void kernel_launch(void* const* d_in, const int* in_sizes, int n_in,
                              void* d_out, int out_size, void* d_ws, size_t ws_size,
                              hipStream_t stream) {
    const float* phi = (const float*)d_in[0];
    const float* X   = (const float*)d_in[1];
    const int M = in_sizes[0] / 120;  // 512
    const int B = in_sizes[1] / 4;    // 4096
    float* z = (float*)d_out;         // z staged directly in d_out

    gmm_main<<<M, 512, 0, stream>>>(phi, X, z, B);
    gmm_norm<<<80, 512, 0, stream>>>(z, M);
}

// Round 7
// 72.016 us; speedup vs baseline: 1.5796x; 1.5796x over previous
//
#include <hip/hip_runtime.h>
#include <math.h>

#define KK 8
#define LOG2E  1.4426950408889634f
#define HL2E   0.7213475204444817f   // 0.5 * log2(e)
#define LOG2PI 1.8378770664093453f

// ---------------------------------------------------------------------------
// Kernel 1: grid = M*4 blocks x 256 threads (4 waves). Block b: m = b>>2,
// points [ (b&3)*1024, +1024 ), 4 points/thread. Small blocks + ~85 VGPR ->
// ~5 blocks/CU resident (vs 2 big barrier-locked blocks in R6) for latency
// hiding (R6: Occupancy 20%, 60% stall at 1x work).
// __builtin_amdgcn_exp2f = bare v_exp_f32 (R6: VALU-issue ~2x static count,
// suspect OCML exp2f expansion).
// resp accumulated as B-scaled sums via wave butterfly + LDS combine + 8
// atomicAdds/block into memset-zeroed z (column z-norm is scale-invariant;
// R5-verified). z layout per row: [mu(32)|logL(32)|pi(8)|resp(8)].
// NOTE: per-point softmax MUST keep max-subtraction (R3 bug: collective exp2
// underflow zeroes responsibility mass).
// NOTE: no 2nd __launch_bounds__ arg (R4: treated as min-blocks/CU -> VGPR=64
// -> 458 MB/dispatch scratch spill).
// ---------------------------------------------------------------------------
__global__ __launch_bounds__(256) void gmm_main(const float* __restrict__ phi,
                                                const float* __restrict__ X,
                                                float* __restrict__ z) {
    __shared__ float4 sp[KK][4];   // per-component params (broadcast reads)
    __shared__ float swr[4][KK];   // per-wave resp partials

    const int b = blockIdx.x;
    const int m = b >> 2;
    const int sub = b & 3;
    const int t = threadIdx.x;
    const float* row = phi + m * 120;

    if (t < KK) {
        // softmax over pi_tilde (redundant across 8 lanes, cheap)
        float mx = row[0];
        #pragma unroll
        for (int j = 1; j < KK; ++j) mx = fmaxf(mx, row[j]);
        float s = 0.f;
        #pragma unroll
        for (int j = 0; j < KK; ++j) s += __expf(row[j] - mx);
        float pik = __expf(row[t] - mx) / s;
        if (sub == 0) z[m * 80 + 64 + t] = pik;          // pi columns

        const float* muk = row + 8 + t * 4;
        const float* Lv  = row + 40 + t * 10;
        // tril(D=4) order: l00,l10,l11,l20,l21,l22,l30,l31,l32,l33
        float l00 = Lv[0], l10 = Lv[1], l11 = Lv[2], l20 = Lv[3], l21 = Lv[4],
              l22 = Lv[5], l30 = Lv[6], l31 = Lv[7], l32 = Lv[8], l33 = Lv[9];
        float i0 = 1.f / l00, i1 = 1.f / l11, i2 = 1.f / l22, i3 = 1.f / l33;
        // W = inv(L), lower triangular (== forward-substitution coefficients)
        float w00 = i0;
        float w10 = -i1 * l10 * w00;
        float w11 = i1;
        float w20 = -i2 * (l20 * w00 + l21 * w10);
        float w21 = -i2 * (l21 * w11);
        float w22 = i2;
        float w30 = -i3 * (l30 * w00 + l31 * w10 + l32 * w20);
        float w31 = -i3 * (l31 * w11 + l32 * w21);
        float w32 = -i3 * (l32 * w22);
        float w33 = i3;
        float logdet = 2.f * (__logf(fmaxf(fabsf(l00), 1e-8f)) +
                              __logf(fmaxf(fabsf(l11), 1e-8f)) +
                              __logf(fmaxf(fabsf(l22), 1e-8f)) +
                              __logf(fmaxf(fabsf(l33), 1e-8f)));
        float c2 = (__logf(fmaxf(pik, 1e-8f)) -
                    0.5f * (4.f * LOG2PI + logdet)) * LOG2E;
        sp[t][0] = make_float4(muk[0], muk[1], muk[2], muk[3]);
        sp[t][1] = make_float4(w00, w10, w11, w20);
        sp[t][2] = make_float4(w21, w22, w30, w31);
        sp[t][3] = make_float4(w32, w33, c2, 0.f);
    } else if (sub == 0 && t >= 64 && t < 96) {          // mu columns
        int j = t - 64;
        z[m * 80 + j] = row[8 + j];
    } else if (sub == 0 && t >= 96 && t < 128) {         // log|L_diag| columns
        int j = t - 96, k = j >> 2, d = j & 3;
        int didx = (d == 0) ? 0 : (d == 1) ? 2 : (d == 2) ? 5 : 9;
        z[m * 80 + 32 + j] = __logf(fmaxf(fabsf(row[40 + k * 10 + didx]), 1e-6f));
    }
    __syncthreads();

    float acc[KK];
    #pragma unroll
    for (int k = 0; k < KK; ++k) acc[k] = 0.f;

    const float4* X4 = reinterpret_cast<const float4*>(X);  // 4096 rows
    float4 xv[4];
    #pragma unroll
    for (int i = 0; i < 4; ++i) xv[i] = X4[sub * 1024 + i * 256 + t];

    float lj[4][KK];
    #pragma unroll
    for (int k = 0; k < KK; ++k) {
        float4 p0 = sp[k][0], p1 = sp[k][1], p2 = sp[k][2], p3 = sp[k][3];
        // mu=p0; w00,w10,w11,w20=p1; w21,w22,w30,w31=p2; w32,w33,c2=p3
        #pragma unroll
        for (int i = 0; i < 4; ++i) {
            float d0 = xv[i].x - p0.x;
            float d1 = xv[i].y - p0.y;
            float d2 = xv[i].z - p0.z;
            float d3 = xv[i].w - p0.w;
            float a0 = d0 * p1.x;
            float a1 = fmaf(p1.y, d0, d1 * p1.z);
            float a2 = fmaf(p1.w, d0, fmaf(p2.x, d1, d2 * p2.y));
            float a3 = fmaf(p2.z, d0, fmaf(p2.w, d1, fmaf(p3.x, d2, d3 * p3.y)));
            float sq = fmaf(a0, a0, fmaf(a1, a1, fmaf(a2, a2, a3 * a3)));
            lj[i][k] = fmaf(-HL2E, sq, p3.z);             // log2-domain
        }
    }
    #pragma unroll
    for (int i = 0; i < 4; ++i) {
        float mx = lj[i][0];
        #pragma unroll
        for (int k = 1; k < KK; ++k) mx = fmaxf(mx, lj[i][k]);
        float e[KK], s = 0.f;
        #pragma unroll
        for (int k = 0; k < KK; ++k) {
            e[k] = __builtin_amdgcn_exp2f(lj[i][k] - mx); // bare v_exp_f32
            s += e[k];
        }
        float inv = __builtin_amdgcn_rcpf(s);             // s >= 1 (max term = 1)
        #pragma unroll
        for (int k = 0; k < KK; ++k) acc[k] = fmaf(e[k], inv, acc[k]);
    }

    // wave butterfly-reduce, stash per wave, combine, one atomic per k
    #pragma unroll
    for (int k = 0; k < KK; ++k) {
        float v = acc[k];
        #pragma unroll
        for (int off = 32; off; off >>= 1) v += __shfl_xor(v, off, 64);
        acc[k] = v;
    }
    if ((t & 63) == 0) {
        int wid = t >> 6;
        #pragma unroll
        for (int k = 0; k < KK; ++k) swr[wid][k] = acc[k];
    }
    __syncthreads();
    if (t < KK) {
        float s = swr[0][t] + swr[1][t] + swr[2][t] + swr[3][t];
        atomicAdd(&z[m * 80 + 72 + t], s);
    }
}

// ---------------------------------------------------------------------------
// Kernel 2: in-place column normalization of z (M=512 rows x 80 cols), ddof=1.
// One block per column, one thread per row; element cached in a register.
// (resp columns hold B-scaled sums; (v-mean)/std is scale-invariant.)
// ---------------------------------------------------------------------------
__global__ __launch_bounds__(512) void gmm_norm(float* __restrict__ z, int M) {
    __shared__ float sw[8];
    const int col = blockIdx.x;
    const int t = threadIdx.x;

    float v = z[t * 80 + col];

    float r = v;
    #pragma unroll
    for (int off = 32; off; off >>= 1) r += __shfl_xor(r, off, 64);
    if ((t & 63) == 0) sw[t >> 6] = r;
    __syncthreads();
    float tot = 0.f;
    #pragma unroll
    for (int w = 0; w < 8; ++w) tot += sw[w];
    float mean = tot / (float)M;
    __syncthreads();

    float d = v - mean;
    r = d * d;
    #pragma unroll
    for (int off = 32; off; off >>= 1) r += __shfl_xor(r, off, 64);
    if ((t & 63) == 0) sw[t >> 6] = r;
    __syncthreads();
    float tot2 = 0.f;
    #pragma unroll
    for (int w = 0; w < 8; ++w) tot2 += sw[w];
    float stdv = fmaxf(sqrtf(tot2 / (float)(M - 1)), 1e-6f);

    z[t * 80 + col] = d / stdv;
}

extern "C" void kernel_launch(void* const* d_in, const int* in_sizes, int n_in,
                              void* d_out, int out_size, void* d_ws, size_t ws_size,
                              hipStream_t stream) {
    const float* phi = (const float*)d_in[0];
    const float* X   = (const float*)d_in[1];
    const int M = in_sizes[0] / 120;  // 512
    float* z = (float*)d_out;         // z staged directly in d_out

    // zero resp accumulators (d_out is poisoned 0xAA before every launch)
    hipMemsetAsync(z, 0, (size_t)out_size * sizeof(float), stream);
    gmm_main<<<M * 4, 256, 0, stream>>>(phi, X, z);
    gmm_norm<<<80, 512, 0, stream>>>(z, M);
}